// Round 8
// baseline (414.379 us; speedup 1.0000x reference)
//
#include <hip/hip_runtime.h>
#include <hip/hip_bf16.h>

#define S_LEN 2048
#define NHEAD 16
#define HDIM 64
#define EMB 1024

typedef short v8s __attribute__((ext_vector_type(8)));
typedef float v4f __attribute__((ext_vector_type(4)));

__device__ __forceinline__ float bflo(unsigned u) {
    union { unsigned u; float f; } v; v.u = u << 16; return v.f;
}
__device__ __forceinline__ float bfhi(unsigned u) {
    union { unsigned u; float f; } v; v.u = u & 0xFFFF0000u; return v.f;
}
// packed f32x2 -> bf16x2 (v_cvt_pk_bf16_f32 on gfx950), RNE
__device__ __forceinline__ unsigned cvtpk(float lo, float hi) {
    union { __hip_bfloat162 h2; unsigned u; } v;
    float2 f; f.x = lo; f.y = hi;
    v.h2 = __float22bfloat162_rn(f);
    return v.u;
}
__device__ __forceinline__ unsigned short f2bf(float f) {
    return (unsigned short)cvtpk(f, f);
}
__device__ __forceinline__ v8s cvt8(float4 a, float4 b) {
    v8s r;
    ((unsigned*)&r)[0] = cvtpk(a.x, a.y);
    ((unsigned*)&r)[1] = cvtpk(a.z, a.w);
    ((unsigned*)&r)[2] = cvtpk(b.x, b.y);
    ((unsigned*)&r)[3] = cvtpk(b.z, b.w);
    return r;
}

// ---------------------------------------------------------------------------
// K1: MFMA projections — R0-VERBATIM (proven 277.7us pipeline member).
// Session record: cvtw-fold (R5/R6) + per-hi Tq (R6) were part of a +26us
// satellite regression; restored exactly.
// ---------------------------------------------------------------------------
__global__ __launch_bounds__(128) void k_proj2(
    const float* __restrict__ q, const float* __restrict__ k, const float* __restrict__ v,
    const float* __restrict__ Wq, const float* __restrict__ Wk, const float* __restrict__ Wv,
    unsigned short* __restrict__ Qp, unsigned short* __restrict__ Kp, unsigned short* __restrict__ Vt)
{
    __shared__ unsigned short Tq[2][16][72];       // wave-private bounce tiles
    const int t = threadIdx.x, wave = t >> 6, lane = t & 63;
    const int l15 = lane & 15, l4 = lane >> 4;
    const int mtx = blockIdx.y;                    // 0:q 1:k 2:v
    const int hq = blockIdx.z;                     // head quarter
    const int row0 = blockIdx.x * 32 + wave * 16;  // global row in [0,4096)
    const int b = row0 >> 11, s0 = row0 & 2047;
    const float* X = (mtx == 0) ? q : (mtx == 1) ? k : v;
    const float* W = (mtx == 0) ? Wq : (mtx == 1) ? Wk : Wv;

    v8s wf[4][2];
    #pragma unroll
    for (int tile = 0; tile < 4; ++tile)
        #pragma unroll
        for (int c2 = 0; c2 < 2; ++c2) {
            const float* wp = W + (tile * 16 + l15) * 64 + c2 * 32 + l4 * 8;
            wf[tile][c2] = cvt8(*(const float4*)wp, *(const float4*)(wp + 4));
        }

    #pragma unroll
    for (int hi = 0; hi < 4; ++hi) {
        const int h = hq * 4 + hi;
        v8s xf[2];
        #pragma unroll
        for (int c2 = 0; c2 < 2; ++c2) {
            const float* xp = X + (size_t)(row0 + l15) * EMB + h * 64 + c2 * 32 + l4 * 8;
            xf[c2] = cvt8(*(const float4*)xp, *(const float4*)(xp + 4));
        }
        v4f acc[4];
        #pragma unroll
        for (int i = 0; i < 4; ++i) acc[i] = (v4f){0.f, 0.f, 0.f, 0.f};
        if (mtx < 2) {
            #pragma unroll
            for (int ns = 0; ns < 4; ++ns)
                #pragma unroll
                for (int c2 = 0; c2 < 2; ++c2)
                    acc[ns] = __builtin_amdgcn_mfma_f32_16x16x32_bf16(xf[c2], wf[ns][c2], acc[ns], 0, 0, 0);
            #pragma unroll
            for (int ns = 0; ns < 4; ++ns)
                #pragma unroll
                for (int r = 0; r < 4; ++r)
                    Tq[wave][l4 * 4 + r][ns * 16 + l15] = f2bf(acc[ns][r]);
            const int row = lane >> 2, c8 = (lane & 3) * 16;
            uint4 d0 = *(const uint4*)&Tq[wave][row][c8];
            uint4 d1 = *(const uint4*)&Tq[wave][row][c8 + 8];
            unsigned short* dst = ((mtx == 0) ? Qp : Kp)
                + (size_t)(b * NHEAD + h) * S_LEN * HDIM + (size_t)(s0 + row) * HDIM + c8;
            *(uint4*)dst = d0;
            *(uint4*)(dst + 8) = d1;
        } else {
            #pragma unroll
            for (int ms = 0; ms < 4; ++ms)
                #pragma unroll
                for (int c2 = 0; c2 < 2; ++c2)
                    acc[ms] = __builtin_amdgcn_mfma_f32_16x16x32_bf16(wf[ms][c2], xf[c2], acc[ms], 0, 0, 0);
            unsigned short* dst = Vt + (size_t)(b * NHEAD + h) * HDIM * S_LEN;
            #pragma unroll
            for (int ms = 0; ms < 4; ++ms)
                #pragma unroll
                for (int r = 0; r < 4; ++r)
                    dst[(size_t)(ms * 16 + l4 * 4 + r) * S_LEN + s0 + l15] = f2bf(acc[ms][r]);
        }
    }
}

// ---------------------------------------------------------------------------
// K1c: W_fc fp32 -> bf16 — R0-VERBATIM (separate kernel restored).
// ---------------------------------------------------------------------------
__global__ __launch_bounds__(256) void k_cvtw(
    const float* __restrict__ W, unsigned short* __restrict__ Wb)
{
    const int i = (blockIdx.x * 256 + threadIdx.x) * 4;
    float4 wv = *(const float4*)(W + i);
    uint2 pk;
    pk.x = cvtpk(wv.x, wv.y);
    pk.y = cvtpk(wv.z, wv.w);
    *(uint2*)(Wb + i) = pk;
}

// ---------------------------------------------------------------------------
// K2: fused attention — R0-VERBATIM (proven 113us).
// ---------------------------------------------------------------------------
__global__ __launch_bounds__(1024, 4) void k_fattn(
    const unsigned short* __restrict__ Qp, const unsigned short* __restrict__ Kp,
    const unsigned short* __restrict__ Vt, unsigned short* __restrict__ Op)
{
    __shared__ unsigned short Pex[16][64][40];   // 80 KiB
    __shared__ unsigned ZrsU[64][20];            // 5 KiB
    const int t = threadIdx.x, wave = t >> 6, lane = t & 63;
    const int l15 = lane & 15, l4 = lane >> 4;
    const int h = wave;
    const int id = blockIdx.x;
    const int slot = id & 7;
    const int kqb = slot & 3;
    const int bsel = slot >> 2;
    const int qt = bsel * 32 + (id >> 3);
    const int b = qt >> 5;
    const int q0 = (qt & 31) * 64;
    const unsigned short* qh = Qp + (size_t)(b * NHEAD + h) * S_LEN * HDIM;
    const unsigned short* kh = Kp + (size_t)(b * NHEAD + h) * S_LEN * HDIM;
    const unsigned short* vh = Vt + (size_t)(b * NHEAD + h) * HDIM * S_LEN;

    v8s aq[4][2];
    #pragma unroll
    for (int qs = 0; qs < 4; ++qs)
        #pragma unroll
        for (int c2 = 0; c2 < 2; ++c2)
            aq[qs][c2] = *(const v8s*)(qh + (size_t)(q0 + qs * 16 + l15) * HDIM + c2 * 32 + l4 * 8);

    v4f o[4][4];
    #pragma unroll
    for (int qs = 0; qs < 4; ++qs)
        #pragma unroll
        for (int ds = 0; ds < 4; ++ds)
            o[qs][ds] = (v4f){0.f, 0.f, 0.f, 0.f};

    const int zq = t >> 4;
    const int zc = t & 15;

    for (int c = 0; c < 16; ++c) {
        const int kk0 = kqb * 512 + c * 32;
        #pragma unroll
        for (int ks = 0; ks < 2; ++ks) {
            const unsigned short* kb = kh + (size_t)(kk0 + ks * 16 + l15) * HDIM + l4 * 8;
            v8s b0 = *(const v8s*)kb;
            v8s b1 = *(const v8s*)(kb + 32);
            #pragma unroll
            for (int qs = 0; qs < 4; ++qs) {
                v4f sf = (v4f){0.f, 0.f, 0.f, 0.f};
                sf = __builtin_amdgcn_mfma_f32_16x16x32_bf16(aq[qs][0], b0, sf, 0, 0, 0);
                sf = __builtin_amdgcn_mfma_f32_16x16x32_bf16(aq[qs][1], b1, sf, 0, 0, 0);
                const int rb = qs * 16 + l4 * 4;
                unsigned p01 = cvtpk(__expf(sf[0] * 0.03125f), __expf(sf[1] * 0.03125f));
                unsigned p23 = cvtpk(__expf(sf[2] * 0.03125f), __expf(sf[3] * 0.03125f));
                Pex[h][rb + 0][ks * 16 + l15] = (unsigned short)p01;
                Pex[h][rb + 1][ks * 16 + l15] = (unsigned short)(p01 >> 16);
                Pex[h][rb + 2][ks * 16 + l15] = (unsigned short)p23;
                Pex[h][rb + 3][ks * 16 + l15] = (unsigned short)(p23 >> 16);
            }
        }
        __syncthreads();
        {
            float z0 = 0.f, z1 = 0.f;
            #pragma unroll
            for (int hh = 0; hh < 16; ++hh) {
                unsigned u = *(const unsigned*)&Pex[hh][zq][zc * 2];
                z0 += bflo(u); z1 += bfhi(u);
            }
            ZrsU[zq][zc] = cvtpk(__builtin_amdgcn_rcpf(z0), __builtin_amdgcn_rcpf(z1));
        }
        __syncthreads();
        {
            v8s bv[4];
            #pragma unroll
            for (int ds = 0; ds < 4; ++ds)
                bv[ds] = *(const v8s*)(vh + (size_t)(ds * 16 + l15) * S_LEN + kk0 + l4 * 8);
            #pragma unroll
            for (int qs = 0; qs < 4; ++qs) {
                uint4 pu = *(const uint4*)&Pex[h][qs * 16 + l15][l4 * 8];
                uint4 zv = *(const uint4*)&ZrsU[qs * 16 + l15][l4 * 4];
                v8s pn;
                ((unsigned*)&pn)[0] = cvtpk(bflo(pu.x) * bflo(zv.x), bfhi(pu.x) * bfhi(zv.x));
                ((unsigned*)&pn)[1] = cvtpk(bflo(pu.y) * bflo(zv.y), bfhi(pu.y) * bfhi(zv.y));
                ((unsigned*)&pn)[2] = cvtpk(bflo(pu.z) * bflo(zv.z), bfhi(pu.z) * bfhi(zv.z));
                ((unsigned*)&pn)[3] = cvtpk(bflo(pu.w) * bflo(zv.w), bfhi(pu.w) * bfhi(zv.w));
                #pragma unroll
                for (int ds = 0; ds < 4; ++ds)
                    o[qs][ds] = __builtin_amdgcn_mfma_f32_16x16x32_bf16(pn, bv[ds], o[qs][ds], 0, 0, 0);
            }
        }
    }

    unsigned short* op = Op + (size_t)(kqb * 2 + b) * S_LEN * EMB;
    #pragma unroll
    for (int qs = 0; qs < 4; ++qs)
        #pragma unroll
        for (int ds = 0; ds < 4; ++ds)
            #pragma unroll
            for (int r = 0; r < 4; ++r)
                op[(size_t)(q0 + qs * 16 + l4 * 4 + r) * EMB + h * 64 + ds * 16 + l15] =
                    f2bf(o[qs][ds][r]);
}

// ---------------------------------------------------------------------------
// K2diag: MEASUREMENT ONLY. Verbatim k_fattn structure, 32 c-iters (c&15),
// with the entire P-elementwise chain ablated: no expf/scale (phase 1 stores
// raw S packed), phase 2 = barrier only (ZrsU kept live via one dummy store
// so LDS_Block_Size stays 87040 -> same 1 block/CU), phase 3 feeds raw P bits
// to PV (no Z read/unpack/mul/repack). Loads, LDS traffic shape, MFMA count,
// barriers all preserved. Writes Op BEFORE the real k_fattn overwrites it ->
// zero correctness impact. Readout: top-5 dur D -> elementwise cost per real
// kernel ~ (222 - D)/2 us. Deliberate one-round dur_us cost ~ +D.
// ---------------------------------------------------------------------------
__global__ __launch_bounds__(1024, 4) void k_diag(
    const unsigned short* __restrict__ Qp, const unsigned short* __restrict__ Kp,
    const unsigned short* __restrict__ Vt, unsigned short* __restrict__ Op)
{
    __shared__ unsigned short Pex[16][64][40];
    __shared__ unsigned ZrsU[64][20];
    const int t = threadIdx.x, wave = t >> 6, lane = t & 63;
    const int l15 = lane & 15, l4 = lane >> 4;
    const int h = wave;
    const int id = blockIdx.x;
    const int slot = id & 7;
    const int kqb = slot & 3;
    const int bsel = slot >> 2;
    const int qt = bsel * 32 + (id >> 3);
    const int b = qt >> 5;
    const int q0 = (qt & 31) * 64;
    const unsigned short* qh = Qp + (size_t)(b * NHEAD + h) * S_LEN * HDIM;
    const unsigned short* kh = Kp + (size_t)(b * NHEAD + h) * S_LEN * HDIM;
    const unsigned short* vh = Vt + (size_t)(b * NHEAD + h) * HDIM * S_LEN;

    if (t < 64) ZrsU[t][0] = 0;   // keep ZrsU allocated: LDS size parity

    v8s aq[4][2];
    #pragma unroll
    for (int qs = 0; qs < 4; ++qs)
        #pragma unroll
        for (int c2 = 0; c2 < 2; ++c2)
            aq[qs][c2] = *(const v8s*)(qh + (size_t)(q0 + qs * 16 + l15) * HDIM + c2 * 32 + l4 * 8);

    v4f o[4][4];
    #pragma unroll
    for (int qs = 0; qs < 4; ++qs)
        #pragma unroll
        for (int ds = 0; ds < 4; ++ds)
            o[qs][ds] = (v4f){0.f, 0.f, 0.f, 0.f};

    for (int cc = 0; cc < 32; ++cc) {
        const int c = cc & 15;
        const int kk0 = kqb * 512 + c * 32;
        // phase 1: QK^T MFMA + raw pack (NO expf, NO scale)
        #pragma unroll
        for (int ks = 0; ks < 2; ++ks) {
            const unsigned short* kb = kh + (size_t)(kk0 + ks * 16 + l15) * HDIM + l4 * 8;
            v8s b0 = *(const v8s*)kb;
            v8s b1 = *(const v8s*)(kb + 32);
            #pragma unroll
            for (int qs = 0; qs < 4; ++qs) {
                v4f sf = (v4f){0.f, 0.f, 0.f, 0.f};
                sf = __builtin_amdgcn_mfma_f32_16x16x32_bf16(aq[qs][0], b0, sf, 0, 0, 0);
                sf = __builtin_amdgcn_mfma_f32_16x16x32_bf16(aq[qs][1], b1, sf, 0, 0, 0);
                const int rb = qs * 16 + l4 * 4;
                unsigned p01 = cvtpk(sf[0], sf[1]);
                unsigned p23 = cvtpk(sf[2], sf[3]);
                Pex[h][rb + 0][ks * 16 + l15] = (unsigned short)p01;
                Pex[h][rb + 1][ks * 16 + l15] = (unsigned short)(p01 >> 16);
                Pex[h][rb + 2][ks * 16 + l15] = (unsigned short)p23;
                Pex[h][rb + 3][ks * 16 + l15] = (unsigned short)(p23 >> 16);
            }
        }
        __syncthreads();
        // phase 2: ablated (barrier only)
        __syncthreads();
        // phase 3: PV MFMA on raw P bits (NO Z read / unpack / mul / repack)
        {
            v8s bv[4];
            #pragma unroll
            for (int ds = 0; ds < 4; ++ds)
                bv[ds] = *(const v8s*)(vh + (size_t)(ds * 16 + l15) * S_LEN + kk0 + l4 * 8);
            #pragma unroll
            for (int qs = 0; qs < 4; ++qs) {
                uint4 pu = *(const uint4*)&Pex[h][qs * 16 + l15][l4 * 8];
                v8s pn;
                ((unsigned*)&pn)[0] = pu.x;
                ((unsigned*)&pn)[1] = pu.y;
                ((unsigned*)&pn)[2] = pu.z;
                ((unsigned*)&pn)[3] = pu.w;
                #pragma unroll
                for (int ds = 0; ds < 4; ++ds)
                    o[qs][ds] = __builtin_amdgcn_mfma_f32_16x16x32_bf16(pn, bv[ds], o[qs][ds], 0, 0, 0);
            }
        }
    }

    unsigned short* op = Op + (size_t)(kqb * 2 + b) * S_LEN * EMB;
    #pragma unroll
    for (int qs = 0; qs < 4; ++qs)
        #pragma unroll
        for (int ds = 0; ds < 4; ++ds)
            #pragma unroll
            for (int r = 0; r < 4; ++r)
                op[(size_t)(q0 + qs * 16 + l4 * 4 + r) * EMB + h * 64 + ds * 16 + l15] =
                    f2bf(o[qs][ds][r]);
}

// ---------------------------------------------------------------------------
// K2b: merge the 4 k-quarter partials -> AO — R0-VERBATIM.
// ---------------------------------------------------------------------------
__global__ __launch_bounds__(256) void k_merge4(
    const unsigned short* __restrict__ Op, unsigned short* __restrict__ AO)
{
    const size_t i = ((size_t)blockIdx.x * 256 + threadIdx.x) * 8;
    const size_t row = i >> 10;
    const int b = (int)(row >> 11);
    const size_t off = (row & 2047) * EMB + (i & 1023);
    float a0 = 0, a1 = 0, a2 = 0, a3 = 0, a4 = 0, a5 = 0, a6 = 0, a7 = 0;
    #pragma unroll
    for (int kq = 0; kq < 4; ++kq) {
        uint4 u = *(const uint4*)(Op + (size_t)(kq * 2 + b) * S_LEN * EMB + off);
        a0 += bflo(u.x); a1 += bfhi(u.x);
        a2 += bflo(u.y); a3 += bfhi(u.y);
        a4 += bflo(u.z); a5 += bfhi(u.z);
        a6 += bflo(u.w); a7 += bfhi(u.w);
    }
    uint4 r;
    r.x = cvtpk(a0, a1); r.y = cvtpk(a2, a3);
    r.z = cvtpk(a4, a5); r.w = cvtpk(a6, a7);
    *(uint4*)(AO + i) = r;
}

// ---------------------------------------------------------------------------
// K4: out = AO @ W_fc^T + b_fc — R0-VERBATIM (32x64 wave tile; the R6 16x64
// retile doubled B-fragment L2 traffic and regressed).
// ---------------------------------------------------------------------------
__global__ __launch_bounds__(256) void k_fc(
    const unsigned short* __restrict__ AO, const unsigned short* __restrict__ Wb,
    const float* __restrict__ bias, float* __restrict__ out)
{
    const int t = threadIdx.x, wave = t >> 6, lane = t & 63;
    const int l15 = lane & 15, l4 = lane >> 4;
    const int m0 = blockIdx.x * 128 + wave * 32;
    const int n0 = blockIdx.y * 64;
    v4f c[2][4];
    #pragma unroll
    for (int i = 0; i < 2; ++i)
        #pragma unroll
        for (int j = 0; j < 4; ++j) c[i][j] = (v4f){0.f, 0.f, 0.f, 0.f};
    for (int k = 0; k < EMB; k += 32) {
        v8s a0 = *(const v8s*)(AO + (size_t)(m0 + l15) * EMB + k + l4 * 8);
        v8s a1 = *(const v8s*)(AO + (size_t)(m0 + 16 + l15) * EMB + k + l4 * 8);
        #pragma unroll
        for (int ns = 0; ns < 4; ++ns) {
            v8s bw = *(const v8s*)(Wb + (size_t)(n0 + ns * 16 + l15) * EMB + k + l4 * 8);
            c[0][ns] = __builtin_amdgcn_mfma_f32_16x16x32_bf16(a0, bw, c[0][ns], 0, 0, 0);
            c[1][ns] = __builtin_amdgcn_mfma_f32_16x16x32_bf16(a1, bw, c[1][ns], 0, 0, 0);
        }
    }
    #pragma unroll
    for (int ms = 0; ms < 2; ++ms)
        #pragma unroll
        for (int ns = 0; ns < 4; ++ns) {
            const float bv = bias[n0 + ns * 16 + l15];
            #pragma unroll
            for (int r = 0; r < 4; ++r)
                out[(size_t)(m0 + ms * 16 + l4 * 4 + r) * EMB + n0 + ns * 16 + l15] = c[ms][ns][r] + bv;
        }
}

extern "C" void kernel_launch(void* const* d_in, const int* in_sizes, int n_in,
                              void* d_out, int out_size, void* d_ws, size_t ws_size,
                              hipStream_t stream)
{
    (void)in_sizes; (void)n_in; (void)out_size; (void)ws_size;
    const float* q   = (const float*)d_in[0];
    const float* k   = (const float*)d_in[1];
    const float* v   = (const float*)d_in[2];
    const float* Wq  = (const float*)d_in[3];
    const float* Wk  = (const float*)d_in[4];
    const float* Wv  = (const float*)d_in[5];
    const float* Wfc = (const float*)d_in[6];
    const float* bfc = (const float*)d_in[7];

    char* w = (char*)d_ws;
    unsigned short* Qp = (unsigned short*)(w);                      //  8 MiB (AO overlays after k_fattn)
    unsigned short* Kp = (unsigned short*)(w + (8u  << 20));        //  8 MiB
    unsigned short* Vt = (unsigned short*)(w + (16u << 20));        //  8 MiB
    unsigned short* Wb = (unsigned short*)(w + (24u << 20));        //  2 MiB
    unsigned short* Op = (unsigned short*)(w + (26u << 20));        // 32 MiB (8 planes)
    unsigned short* AO = Qp;                                        // reuse (Qp dead post-attn)

    k_proj2 <<<dim3(128, 3, 4), dim3(128),  0, stream>>>(q, k, v, Wq, Wk, Wv, Qp, Kp, Vt);
    k_cvtw  <<<dim3(1024),      dim3(256),  0, stream>>>(Wfc, Wb);
    k_diag  <<<dim3(256),       dim3(1024), 0, stream>>>(Qp, Kp, Vt, Op);   // diagnostic; Op fully overwritten below
    k_fattn <<<dim3(256),       dim3(1024), 0, stream>>>(Qp, Kp, Vt, Op);
    k_merge4<<<dim3(2048),      dim3(256),  0, stream>>>(Op, AO);
    k_fc    <<<dim3(32, 16),    dim3(256),  0, stream>>>(AO, Wb, bfc, (float*)d_out);
}

// Round 9
// 287.145 us; speedup vs baseline: 1.4431x; 1.4431x over previous
//
#include <hip/hip_runtime.h>
#include <hip/hip_bf16.h>

#define S_LEN 2048
#define NHEAD 16
#define HDIM 64
#define EMB 1024

typedef short v8s __attribute__((ext_vector_type(8)));
typedef float v4f __attribute__((ext_vector_type(4)));

#if __has_builtin(__builtin_amdgcn_exp2f)
#define EXP2(x) __builtin_amdgcn_exp2f(x)
#else
#define EXP2(x) exp2f(x)
#endif

__device__ __forceinline__ float bflo(unsigned u) {
    union { unsigned u; float f; } v; v.u = u << 16; return v.f;
}
__device__ __forceinline__ float bfhi(unsigned u) {
    union { unsigned u; float f; } v; v.u = u & 0xFFFF0000u; return v.f;
}
// packed f32x2 -> bf16x2 (v_cvt_pk_bf16_f32 on gfx950), RNE
__device__ __forceinline__ unsigned cvtpk(float lo, float hi) {
    union { __hip_bfloat162 h2; unsigned u; } v;
    float2 f; f.x = lo; f.y = hi;
    v.h2 = __float22bfloat162_rn(f);
    return v.u;
}
__device__ __forceinline__ unsigned short f2bf(float f) {
    return (unsigned short)cvtpk(f, f);
}
__device__ __forceinline__ v8s cvt8(float4 a, float4 b) {
    v8s r;
    ((unsigned*)&r)[0] = cvtpk(a.x, a.y);
    ((unsigned*)&r)[1] = cvtpk(a.z, a.w);
    ((unsigned*)&r)[2] = cvtpk(b.x, b.y);
    ((unsigned*)&r)[3] = cvtpk(b.z, b.w);
    return r;
}

// ---------------------------------------------------------------------------
// K1: MFMA projections — R0 structure; Q additionally scaled by log2(e)/32
// (v5-VERIFIED fold: softmax 1/sqrt(EMB) + e->2 base change move into the Q
// operand so k_fattn's phase 1 is a bare v_exp). K/V paths unchanged.
// ---------------------------------------------------------------------------
__global__ __launch_bounds__(128) void k_proj2(
    const float* __restrict__ q, const float* __restrict__ k, const float* __restrict__ v,
    const float* __restrict__ Wq, const float* __restrict__ Wk, const float* __restrict__ Wv,
    unsigned short* __restrict__ Qp, unsigned short* __restrict__ Kp, unsigned short* __restrict__ Vt)
{
    __shared__ unsigned short Tq[2][16][72];       // wave-private bounce tiles
    const int t = threadIdx.x, wave = t >> 6, lane = t & 63;
    const int l15 = lane & 15, l4 = lane >> 4;
    const int mtx = blockIdx.y;                    // 0:q 1:k 2:v
    const int hq = blockIdx.z;                     // head quarter
    const int row0 = blockIdx.x * 32 + wave * 16;  // global row in [0,4096)
    const int b = row0 >> 11, s0 = row0 & 2047;
    const float* X = (mtx == 0) ? q : (mtx == 1) ? k : v;
    const float* W = (mtx == 0) ? Wq : (mtx == 1) ? Wk : Wv;
    const float qsc = (mtx == 0) ? 0.04508422002778011f : 1.0f;  // log2(e)/32

    v8s wf[4][2];
    #pragma unroll
    for (int tile = 0; tile < 4; ++tile)
        #pragma unroll
        for (int c2 = 0; c2 < 2; ++c2) {
            const float* wp = W + (tile * 16 + l15) * 64 + c2 * 32 + l4 * 8;
            wf[tile][c2] = cvt8(*(const float4*)wp, *(const float4*)(wp + 4));
        }

    #pragma unroll
    for (int hi = 0; hi < 4; ++hi) {
        const int h = hq * 4 + hi;
        v8s xf[2];
        #pragma unroll
        for (int c2 = 0; c2 < 2; ++c2) {
            const float* xp = X + (size_t)(row0 + l15) * EMB + h * 64 + c2 * 32 + l4 * 8;
            xf[c2] = cvt8(*(const float4*)xp, *(const float4*)(xp + 4));
        }
        v4f acc[4];
        #pragma unroll
        for (int i = 0; i < 4; ++i) acc[i] = (v4f){0.f, 0.f, 0.f, 0.f};
        if (mtx < 2) {
            #pragma unroll
            for (int ns = 0; ns < 4; ++ns)
                #pragma unroll
                for (int c2 = 0; c2 < 2; ++c2)
                    acc[ns] = __builtin_amdgcn_mfma_f32_16x16x32_bf16(xf[c2], wf[ns][c2], acc[ns], 0, 0, 0);
            // stage C-frags (col=l15, rows l4*4+r) in LDS, wave-private
            #pragma unroll
            for (int ns = 0; ns < 4; ++ns)
                #pragma unroll
                for (int r = 0; r < 4; ++r)
                    Tq[wave][l4 * 4 + r][ns * 16 + l15] = f2bf(acc[ns][r] * qsc);
            // read back row-major, coalesced global store (lgkmcnt auto)
            const int row = lane >> 2, c8 = (lane & 3) * 16;
            uint4 d0 = *(const uint4*)&Tq[wave][row][c8];
            uint4 d1 = *(const uint4*)&Tq[wave][row][c8 + 8];
            unsigned short* dst = ((mtx == 0) ? Qp : Kp)
                + (size_t)(b * NHEAD + h) * S_LEN * HDIM + (size_t)(s0 + row) * HDIM + c8;
            *(uint4*)dst = d0;
            *(uint4*)(dst + 8) = d1;
        } else {
            #pragma unroll
            for (int ms = 0; ms < 4; ++ms)
                #pragma unroll
                for (int c2 = 0; c2 < 2; ++c2)
                    acc[ms] = __builtin_amdgcn_mfma_f32_16x16x32_bf16(wf[ms][c2], xf[c2], acc[ms], 0, 0, 0);
            unsigned short* dst = Vt + (size_t)(b * NHEAD + h) * HDIM * S_LEN;
            #pragma unroll
            for (int ms = 0; ms < 4; ++ms)
                #pragma unroll
                for (int r = 0; r < 4; ++r)
                    dst[(size_t)(ms * 16 + l4 * 4 + r) * S_LEN + s0 + l15] = f2bf(acc[ms][r]);
        }
    }
}

// ---------------------------------------------------------------------------
// K1c: W_fc fp32 -> bf16 — R0-VERBATIM.
// ---------------------------------------------------------------------------
__global__ __launch_bounds__(256) void k_cvtw(
    const float* __restrict__ W, unsigned short* __restrict__ Wb)
{
    const int i = (blockIdx.x * 256 + threadIdx.x) * 4;
    float4 wv = *(const float4*)(W + i);
    uint2 pk;
    pk.x = cvtpk(wv.x, wv.y);
    pk.y = cvtpk(wv.z, wv.w);
    *(uint2*)(Wb + i) = pk;
}

// ---------------------------------------------------------------------------
// K2: fused attention. R0 structure/barriers/layout EXACTLY, with the two
// elementwise cuts justified by the R8 ablation (skeleton 75us, elementwise
// 38us of the 113):
//  - phase 1: bare v_exp (scale pre-folded into Q by k_proj2; v5-verified).
//  - phase 2: after computing f32 zr, writes NORMALIZED P back into Pex for
//    all 16 heads; ZrsU deleted (LDS 87040->81920, same 1 block/CU).
//  - phase 3: pn = raw uint4 bits from Pex (no unpack/zv/mul/repack).
// Hazards unchanged: phase-2's cross-plane writes sit between the two
// existing barriers; phase 3 & next-phase-1 touch only their own wave's
// plane, so the no-3rd-barrier argument is preserved.
// Session record: v2/v3 pipelining and v4/v5 layout changes all regressed
// (128-reg wall at block=1024; conflict analysis wrong at 20-dword stride).
// Do not restructure the skeleton — it is latency/barrier-bound at ~75us.
// ---------------------------------------------------------------------------
__global__ __launch_bounds__(1024, 4) void k_fattn(
    const unsigned short* __restrict__ Qp, const unsigned short* __restrict__ Kp,
    const unsigned short* __restrict__ Vt, unsigned short* __restrict__ Op)
{
    __shared__ unsigned short Pex[16][64][40];   // 80 KiB (rows 80B: 16B-aligned)
    const int t = threadIdx.x, wave = t >> 6, lane = t & 63;
    const int l15 = lane & 15, l4 = lane >> 4;
    const int h = wave;
    const int id = blockIdx.x;
    const int slot = id & 7;
    const int kqb = slot & 3;         // k-quarter 0..3
    const int bsel = slot >> 2;       // batch
    const int qt = bsel * 32 + (id >> 3);   // q-tile of 64 rows, 0..63
    const int b = qt >> 5;
    const int q0 = (qt & 31) * 64;          // s-offset within batch
    const unsigned short* qh = Qp + (size_t)(b * NHEAD + h) * S_LEN * HDIM;
    const unsigned short* kh = Kp + (size_t)(b * NHEAD + h) * S_LEN * HDIM;
    const unsigned short* vh = Vt + (size_t)(b * NHEAD + h) * HDIM * S_LEN;

    v8s aq[4][2];
    #pragma unroll
    for (int qs = 0; qs < 4; ++qs)
        #pragma unroll
        for (int c2 = 0; c2 < 2; ++c2)
            aq[qs][c2] = *(const v8s*)(qh + (size_t)(q0 + qs * 16 + l15) * HDIM + c2 * 32 + l4 * 8);

    v4f o[4][4];
    #pragma unroll
    for (int qs = 0; qs < 4; ++qs)
        #pragma unroll
        for (int ds = 0; ds < 4; ++ds)
            o[qs][ds] = (v4f){0.f, 0.f, 0.f, 0.f};

    const int zq = t >> 4;          // 0..63: q row for Z-reduce
    const int zc = t & 15;          // col-pair index (2 cols each)

    for (int c = 0; c < 16; ++c) {
        const int kk0 = kqb * 512 + c * 32;
        // ---- phase 1: S = Q K^T (64q x 32k), exp2 -> Pex (wave-private) ---
        #pragma unroll
        for (int ks = 0; ks < 2; ++ks) {
            const unsigned short* kb = kh + (size_t)(kk0 + ks * 16 + l15) * HDIM + l4 * 8;
            v8s b0 = *(const v8s*)kb;
            v8s b1 = *(const v8s*)(kb + 32);
            #pragma unroll
            for (int qs = 0; qs < 4; ++qs) {
                v4f sf = (v4f){0.f, 0.f, 0.f, 0.f};
                sf = __builtin_amdgcn_mfma_f32_16x16x32_bf16(aq[qs][0], b0, sf, 0, 0, 0);
                sf = __builtin_amdgcn_mfma_f32_16x16x32_bf16(aq[qs][1], b1, sf, 0, 0, 0);
                const int rb = qs * 16 + l4 * 4;
                unsigned p01 = cvtpk(EXP2(sf[0]), EXP2(sf[1]));
                unsigned p23 = cvtpk(EXP2(sf[2]), EXP2(sf[3]));
                Pex[h][rb + 0][ks * 16 + l15] = (unsigned short)p01;
                Pex[h][rb + 1][ks * 16 + l15] = (unsigned short)(p01 >> 16);
                Pex[h][rb + 2][ks * 16 + l15] = (unsigned short)p23;
                Pex[h][rb + 3][ks * 16 + l15] = (unsigned short)(p23 >> 16);
            }
        }
        __syncthreads();
        // ---- phase 2 (all 1024 threads): z = sum_h exp; write back P*zr ---
        {
            float z0 = 0.f, z1 = 0.f;
            #pragma unroll
            for (int hh = 0; hh < 16; ++hh) {
                unsigned u = *(const unsigned*)&Pex[hh][zq][zc * 2];
                z0 += bflo(u); z1 += bfhi(u);
            }
            const float zr0 = __builtin_amdgcn_rcpf(z0);
            const float zr1 = __builtin_amdgcn_rcpf(z1);
            #pragma unroll
            for (int hh = 0; hh < 16; ++hh) {
                unsigned u = *(const unsigned*)&Pex[hh][zq][zc * 2];
                *(unsigned*)&Pex[hh][zq][zc * 2] = cvtpk(bflo(u) * zr0, bfhi(u) * zr1);
            }
        }
        __syncthreads();
        // ---- phase 3: pn = raw normalized bits + PV MFMA (k=32) -----------
        {
            v8s bv[4];
            #pragma unroll
            for (int ds = 0; ds < 4; ++ds)
                bv[ds] = *(const v8s*)(vh + (size_t)(ds * 16 + l15) * S_LEN + kk0 + l4 * 8);
            #pragma unroll
            for (int qs = 0; qs < 4; ++qs) {
                uint4 pu = *(const uint4*)&Pex[h][qs * 16 + l15][l4 * 8];
                v8s pn;
                ((unsigned*)&pn)[0] = pu.x;
                ((unsigned*)&pn)[1] = pu.y;
                ((unsigned*)&pn)[2] = pu.z;
                ((unsigned*)&pn)[3] = pu.w;
                #pragma unroll
                for (int ds = 0; ds < 4; ++ds)
                    o[qs][ds] = __builtin_amdgcn_mfma_f32_16x16x32_bf16(pn, bv[ds], o[qs][ds], 0, 0, 0);
            }
        }
        // no 3rd barrier: Pex[h] is wave-private for phase 3 / next phase 1;
        // phase 2's cross-plane accesses are fenced by the two barriers.
    }

    // partial O plane for this (k-quarter, b), bf16
    unsigned short* op = Op + (size_t)(kqb * 2 + b) * S_LEN * EMB;
    #pragma unroll
    for (int qs = 0; qs < 4; ++qs)
        #pragma unroll
        for (int ds = 0; ds < 4; ++ds)
            #pragma unroll
            for (int r = 0; r < 4; ++r)
                op[(size_t)(q0 + qs * 16 + l4 * 4 + r) * EMB + h * 64 + ds * 16 + l15] =
                    f2bf(o[qs][ds][r]);
}

// ---------------------------------------------------------------------------
// K2b: merge the 4 k-quarter partials -> AO — R0-VERBATIM.
// ---------------------------------------------------------------------------
__global__ __launch_bounds__(256) void k_merge4(
    const unsigned short* __restrict__ Op, unsigned short* __restrict__ AO)
{
    const size_t i = ((size_t)blockIdx.x * 256 + threadIdx.x) * 8;
    const size_t row = i >> 10;                 // 0..4095
    const int b = (int)(row >> 11);
    const size_t off = (row & 2047) * EMB + (i & 1023);
    float a0 = 0, a1 = 0, a2 = 0, a3 = 0, a4 = 0, a5 = 0, a6 = 0, a7 = 0;
    #pragma unroll
    for (int kq = 0; kq < 4; ++kq) {
        uint4 u = *(const uint4*)(Op + (size_t)(kq * 2 + b) * S_LEN * EMB + off);
        a0 += bflo(u.x); a1 += bfhi(u.x);
        a2 += bflo(u.y); a3 += bfhi(u.y);
        a4 += bflo(u.z); a5 += bfhi(u.z);
        a6 += bflo(u.w); a7 += bfhi(u.w);
    }
    uint4 r;
    r.x = cvtpk(a0, a1); r.y = cvtpk(a2, a3);
    r.z = cvtpk(a4, a5); r.w = cvtpk(a6, a7);
    *(uint4*)(AO + i) = r;
}

// ---------------------------------------------------------------------------
// K4: out = AO @ W_fc^T + b_fc — R0-VERBATIM (32x64 wave tile).
// ---------------------------------------------------------------------------
__global__ __launch_bounds__(256) void k_fc(
    const unsigned short* __restrict__ AO, const unsigned short* __restrict__ Wb,
    const float* __restrict__ bias, float* __restrict__ out)
{
    const int t = threadIdx.x, wave = t >> 6, lane = t & 63;
    const int l15 = lane & 15, l4 = lane >> 4;
    const int m0 = blockIdx.x * 128 + wave * 32;
    const int n0 = blockIdx.y * 64;
    v4f c[2][4];
    #pragma unroll
    for (int i = 0; i < 2; ++i)
        #pragma unroll
        for (int j = 0; j < 4; ++j) c[i][j] = (v4f){0.f, 0.f, 0.f, 0.f};
    for (int k = 0; k < EMB; k += 32) {
        v8s a0 = *(const v8s*)(AO + (size_t)(m0 + l15) * EMB + k + l4 * 8);
        v8s a1 = *(const v8s*)(AO + (size_t)(m0 + 16 + l15) * EMB + k + l4 * 8);
        #pragma unroll
        for (int ns = 0; ns < 4; ++ns) {
            v8s bw = *(const v8s*)(Wb + (size_t)(n0 + ns * 16 + l15) * EMB + k + l4 * 8);
            c[0][ns] = __builtin_amdgcn_mfma_f32_16x16x32_bf16(a0, bw, c[0][ns], 0, 0, 0);
            c[1][ns] = __builtin_amdgcn_mfma_f32_16x16x32_bf16(a1, bw, c[1][ns], 0, 0, 0);
        }
    }
    #pragma unroll
    for (int ms = 0; ms < 2; ++ms)
        #pragma unroll
        for (int ns = 0; ns < 4; ++ns) {
            const float bv = bias[n0 + ns * 16 + l15];
            #pragma unroll
            for (int r = 0; r < 4; ++r)
                out[(size_t)(m0 + ms * 16 + l4 * 4 + r) * EMB + n0 + ns * 16 + l15] = c[ms][ns][r] + bv;
        }
}

extern "C" void kernel_launch(void* const* d_in, const int* in_sizes, int n_in,
                              void* d_out, int out_size, void* d_ws, size_t ws_size,
                              hipStream_t stream)
{
    (void)in_sizes; (void)n_in; (void)out_size; (void)ws_size;
    const float* q   = (const float*)d_in[0];
    const float* k   = (const float*)d_in[1];
    const float* v   = (const float*)d_in[2];
    const float* Wq  = (const float*)d_in[3];
    const float* Wk  = (const float*)d_in[4];
    const float* Wv  = (const float*)d_in[5];
    const float* Wfc = (const float*)d_in[6];
    const float* bfc = (const float*)d_in[7];

    char* w = (char*)d_ws;
    unsigned short* Qp = (unsigned short*)(w);                      //  8 MiB (AO overlays after k_fattn)
    unsigned short* Kp = (unsigned short*)(w + (8u  << 20));        //  8 MiB
    unsigned short* Vt = (unsigned short*)(w + (16u << 20));        //  8 MiB
    unsigned short* Wb = (unsigned short*)(w + (24u << 20));        //  2 MiB
    unsigned short* Op = (unsigned short*)(w + (26u << 20));        // 32 MiB (8 planes)
    unsigned short* AO = Qp;                                        // reuse (Qp dead post-attn)

    k_proj2 <<<dim3(128, 3, 4), dim3(128),  0, stream>>>(q, k, v, Wq, Wk, Wv, Qp, Kp, Vt);
    k_cvtw  <<<dim3(1024),      dim3(256),  0, stream>>>(Wfc, Wb);
    k_fattn <<<dim3(256),       dim3(1024), 0, stream>>>(Qp, Kp, Vt, Op);
    k_merge4<<<dim3(2048),      dim3(256),  0, stream>>>(Op, AO);
    k_fc    <<<dim3(32, 16),    dim3(256),  0, stream>>>(AO, Wb, bfc, (float*)d_out);
}

// Round 10
// 278.171 us; speedup vs baseline: 1.4897x; 1.0323x over previous
//
#include <hip/hip_runtime.h>
#include <hip/hip_bf16.h>

#define S_LEN 2048
#define NHEAD 16
#define HDIM 64
#define EMB 1024

typedef short v8s __attribute__((ext_vector_type(8)));
typedef float v4f __attribute__((ext_vector_type(4)));

#if __has_builtin(__builtin_amdgcn_exp2f)
#define EXP2(x) __builtin_amdgcn_exp2f(x)
#else
#define EXP2(x) exp2f(x)
#endif

__device__ __forceinline__ float bflo(unsigned u) {
    union { unsigned u; float f; } v; v.u = u << 16; return v.f;
}
__device__ __forceinline__ float bfhi(unsigned u) {
    union { unsigned u; float f; } v; v.u = u & 0xFFFF0000u; return v.f;
}
// packed f32x2 -> bf16x2 (v_cvt_pk_bf16_f32 on gfx950), RNE
__device__ __forceinline__ unsigned cvtpk(float lo, float hi) {
    union { __hip_bfloat162 h2; unsigned u; } v;
    float2 f; f.x = lo; f.y = hi;
    v.h2 = __float22bfloat162_rn(f);
    return v.u;
}
__device__ __forceinline__ unsigned short f2bf(float f) {
    return (unsigned short)cvtpk(f, f);
}
__device__ __forceinline__ v8s cvt8(float4 a, float4 b) {
    v8s r;
    ((unsigned*)&r)[0] = cvtpk(a.x, a.y);
    ((unsigned*)&r)[1] = cvtpk(a.z, a.w);
    ((unsigned*)&r)[2] = cvtpk(b.x, b.y);
    ((unsigned*)&r)[3] = cvtpk(b.z, b.w);
    return r;
}

// ---------------------------------------------------------------------------
// K1: MFMA projections — R0 structure; Q additionally scaled by log2(e)/32
// (fold validated passing in R4/v5 and R9: softmax 1/sqrt(EMB) + e->2 base
// change move into the Q operand so k_fattn phase 1 is a bare v_exp).
// K/V paths unchanged.
// ---------------------------------------------------------------------------
__global__ __launch_bounds__(128) void k_proj2(
    const float* __restrict__ q, const float* __restrict__ k, const float* __restrict__ v,
    const float* __restrict__ Wq, const float* __restrict__ Wk, const float* __restrict__ Wv,
    unsigned short* __restrict__ Qp, unsigned short* __restrict__ Kp, unsigned short* __restrict__ Vt)
{
    __shared__ unsigned short Tq[2][16][72];       // wave-private bounce tiles
    const int t = threadIdx.x, wave = t >> 6, lane = t & 63;
    const int l15 = lane & 15, l4 = lane >> 4;
    const int mtx = blockIdx.y;                    // 0:q 1:k 2:v
    const int hq = blockIdx.z;                     // head quarter
    const int row0 = blockIdx.x * 32 + wave * 16;  // global row in [0,4096)
    const int b = row0 >> 11, s0 = row0 & 2047;
    const float* X = (mtx == 0) ? q : (mtx == 1) ? k : v;
    const float* W = (mtx == 0) ? Wq : (mtx == 1) ? Wk : Wv;
    const float qsc = (mtx == 0) ? 0.04508422002778011f : 1.0f;  // log2(e)/32

    v8s wf[4][2];
    #pragma unroll
    for (int tile = 0; tile < 4; ++tile)
        #pragma unroll
        for (int c2 = 0; c2 < 2; ++c2) {
            const float* wp = W + (tile * 16 + l15) * 64 + c2 * 32 + l4 * 8;
            wf[tile][c2] = cvt8(*(const float4*)wp, *(const float4*)(wp + 4));
        }

    #pragma unroll
    for (int hi = 0; hi < 4; ++hi) {
        const int h = hq * 4 + hi;
        v8s xf[2];
        #pragma unroll
        for (int c2 = 0; c2 < 2; ++c2) {
            const float* xp = X + (size_t)(row0 + l15) * EMB + h * 64 + c2 * 32 + l4 * 8;
            xf[c2] = cvt8(*(const float4*)xp, *(const float4*)(xp + 4));
        }
        v4f acc[4];
        #pragma unroll
        for (int i = 0; i < 4; ++i) acc[i] = (v4f){0.f, 0.f, 0.f, 0.f};
        if (mtx < 2) {
            #pragma unroll
            for (int ns = 0; ns < 4; ++ns)
                #pragma unroll
                for (int c2 = 0; c2 < 2; ++c2)
                    acc[ns] = __builtin_amdgcn_mfma_f32_16x16x32_bf16(xf[c2], wf[ns][c2], acc[ns], 0, 0, 0);
            // stage C-frags (col=l15, rows l4*4+r) in LDS, wave-private
            #pragma unroll
            for (int ns = 0; ns < 4; ++ns)
                #pragma unroll
                for (int r = 0; r < 4; ++r)
                    Tq[wave][l4 * 4 + r][ns * 16 + l15] = f2bf(acc[ns][r] * qsc);
            // read back row-major, coalesced global store (lgkmcnt auto)
            const int row = lane >> 2, c8 = (lane & 3) * 16;
            uint4 d0 = *(const uint4*)&Tq[wave][row][c8];
            uint4 d1 = *(const uint4*)&Tq[wave][row][c8 + 8];
            unsigned short* dst = ((mtx == 0) ? Qp : Kp)
                + (size_t)(b * NHEAD + h) * S_LEN * HDIM + (size_t)(s0 + row) * HDIM + c8;
            *(uint4*)dst = d0;
            *(uint4*)(dst + 8) = d1;
        } else {
            #pragma unroll
            for (int ms = 0; ms < 4; ++ms)
                #pragma unroll
                for (int c2 = 0; c2 < 2; ++c2)
                    acc[ms] = __builtin_amdgcn_mfma_f32_16x16x32_bf16(wf[ms][c2], xf[c2], acc[ms], 0, 0, 0);
            unsigned short* dst = Vt + (size_t)(b * NHEAD + h) * HDIM * S_LEN;
            #pragma unroll
            for (int ms = 0; ms < 4; ++ms)
                #pragma unroll
                for (int r = 0; r < 4; ++r)
                    dst[(size_t)(ms * 16 + l4 * 4 + r) * S_LEN + s0 + l15] = f2bf(acc[ms][r]);
        }
    }
}

// ---------------------------------------------------------------------------
// K1c: W_fc fp32 -> bf16 — R0-VERBATIM.
// ---------------------------------------------------------------------------
__global__ __launch_bounds__(256) void k_cvtw(
    const float* __restrict__ W, unsigned short* __restrict__ Wb)
{
    const int i = (blockIdx.x * 256 + threadIdx.x) * 4;
    float4 wv = *(const float4*)(W + i);
    uint2 pk;
    pk.x = cvtpk(wv.x, wv.y);
    pk.y = cvtpk(wv.z, wv.w);
    *(uint2*)(Wb + i) = pk;
}

// ---------------------------------------------------------------------------
// K2: fused attention — R0-VERBATIM phases 2 & 3 + ZrsU; ONLY phase 1 differs
// (bare v_exp; scale pre-folded into Q). Single-variable isolation of the
// exp2-fold after R9's bundle regressed:
//   R9 post-mortem: normalize-in-phase-2 moved work onto the shared LDS pipe
//   (16 RMW writes/thread, conflicts 4.3M->7.2M, ~+10us pipe occupancy) while
//   the phase-3 work it deleted was partially hidden under MFMA/V-loads.
//   Relocation is only a win if the destination phase has slack on the
//   relocated resource — phase 2 has none (all-thread LDS convoy).
// Session record: v2/v3 pipelining, v4/v5 layout, R9 writeback all regressed.
// Skeleton is barrier/latency-bound at ~75us (R8 ablation); elementwise ~38us.
// ---------------------------------------------------------------------------
__global__ __launch_bounds__(1024, 4) void k_fattn(
    const unsigned short* __restrict__ Qp, const unsigned short* __restrict__ Kp,
    const unsigned short* __restrict__ Vt, unsigned short* __restrict__ Op)
{
    __shared__ unsigned short Pex[16][64][40];   // 80 KiB (rows 80B: 16B-aligned)
    __shared__ unsigned ZrsU[64][20];            // 5 KiB, bf16x2 packed, 80B rows
    const int t = threadIdx.x, wave = t >> 6, lane = t & 63;
    const int l15 = lane & 15, l4 = lane >> 4;
    const int h = wave;
    const int id = blockIdx.x;
    const int slot = id & 7;
    const int kqb = slot & 3;         // k-quarter 0..3
    const int bsel = slot >> 2;       // batch
    const int qt = bsel * 32 + (id >> 3);   // q-tile of 64 rows, 0..63
    const int b = qt >> 5;
    const int q0 = (qt & 31) * 64;          // s-offset within batch
    const unsigned short* qh = Qp + (size_t)(b * NHEAD + h) * S_LEN * HDIM;
    const unsigned short* kh = Kp + (size_t)(b * NHEAD + h) * S_LEN * HDIM;
    const unsigned short* vh = Vt + (size_t)(b * NHEAD + h) * HDIM * S_LEN;

    v8s aq[4][2];
    #pragma unroll
    for (int qs = 0; qs < 4; ++qs)
        #pragma unroll
        for (int c2 = 0; c2 < 2; ++c2)
            aq[qs][c2] = *(const v8s*)(qh + (size_t)(q0 + qs * 16 + l15) * HDIM + c2 * 32 + l4 * 8);

    v4f o[4][4];
    #pragma unroll
    for (int qs = 0; qs < 4; ++qs)
        #pragma unroll
        for (int ds = 0; ds < 4; ++ds)
            o[qs][ds] = (v4f){0.f, 0.f, 0.f, 0.f};

    const int zq = t >> 4;          // 0..63: q row for Z-reduce
    const int zc = t & 15;          // col-pair index (2 cols each)

    for (int c = 0; c < 16; ++c) {
        const int kk0 = kqb * 512 + c * 32;
        // ---- phase 1: S = Q K^T (64q x 32k), bare exp2 -> Pex -------------
        #pragma unroll
        for (int ks = 0; ks < 2; ++ks) {
            const unsigned short* kb = kh + (size_t)(kk0 + ks * 16 + l15) * HDIM + l4 * 8;
            v8s b0 = *(const v8s*)kb;
            v8s b1 = *(const v8s*)(kb + 32);
            #pragma unroll
            for (int qs = 0; qs < 4; ++qs) {
                v4f sf = (v4f){0.f, 0.f, 0.f, 0.f};
                sf = __builtin_amdgcn_mfma_f32_16x16x32_bf16(aq[qs][0], b0, sf, 0, 0, 0);
                sf = __builtin_amdgcn_mfma_f32_16x16x32_bf16(aq[qs][1], b1, sf, 0, 0, 0);
                const int rb = qs * 16 + l4 * 4;
                unsigned p01 = cvtpk(EXP2(sf[0]), EXP2(sf[1]));
                unsigned p23 = cvtpk(EXP2(sf[2]), EXP2(sf[3]));
                Pex[h][rb + 0][ks * 16 + l15] = (unsigned short)p01;
                Pex[h][rb + 1][ks * 16 + l15] = (unsigned short)(p01 >> 16);
                Pex[h][rb + 2][ks * 16 + l15] = (unsigned short)p23;
                Pex[h][rb + 3][ks * 16 + l15] = (unsigned short)(p23 >> 16);
            }
        }
        __syncthreads();
        // ---- phase 2 (all 1024 threads): Zr = 1/sum_h exp, packed bf16 ----
        {
            float z0 = 0.f, z1 = 0.f;
            #pragma unroll
            for (int hh = 0; hh < 16; ++hh) {
                unsigned u = *(const unsigned*)&Pex[hh][zq][zc * 2];
                z0 += bflo(u); z1 += bfhi(u);
            }
            ZrsU[zq][zc] = cvtpk(__builtin_amdgcn_rcpf(z0), __builtin_amdgcn_rcpf(z1));
        }
        __syncthreads();
        // ---- phase 3: normalize P (A-frag order) + PV MFMA (k=32) ----
        {
            v8s bv[4];
            #pragma unroll
            for (int ds = 0; ds < 4; ++ds)
                bv[ds] = *(const v8s*)(vh + (size_t)(ds * 16 + l15) * S_LEN + kk0 + l4 * 8);
            #pragma unroll
            for (int qs = 0; qs < 4; ++qs) {
                uint4 pu = *(const uint4*)&Pex[h][qs * 16 + l15][l4 * 8];
                uint4 zv = *(const uint4*)&ZrsU[qs * 16 + l15][l4 * 4];
                v8s pn;
                ((unsigned*)&pn)[0] = cvtpk(bflo(pu.x) * bflo(zv.x), bfhi(pu.x) * bfhi(zv.x));
                ((unsigned*)&pn)[1] = cvtpk(bflo(pu.y) * bflo(zv.y), bfhi(pu.y) * bfhi(zv.y));
                ((unsigned*)&pn)[2] = cvtpk(bflo(pu.z) * bflo(zv.z), bfhi(pu.z) * bfhi(zv.z));
                ((unsigned*)&pn)[3] = cvtpk(bflo(pu.w) * bflo(zv.w), bfhi(pu.w) * bfhi(zv.w));
                #pragma unroll
                for (int ds = 0; ds < 4; ++ds)
                    o[qs][ds] = __builtin_amdgcn_mfma_f32_16x16x32_bf16(pn, bv[ds], o[qs][ds], 0, 0, 0);
            }
        }
        // no 3rd barrier: Pex[h] is wave-private; ZrsU rewrite ordered by the
        // next iteration's two barriers.
    }

    // partial O plane for this (k-quarter, b), bf16
    unsigned short* op = Op + (size_t)(kqb * 2 + b) * S_LEN * EMB;
    #pragma unroll
    for (int qs = 0; qs < 4; ++qs)
        #pragma unroll
        for (int ds = 0; ds < 4; ++ds)
            #pragma unroll
            for (int r = 0; r < 4; ++r)
                op[(size_t)(q0 + qs * 16 + l4 * 4 + r) * EMB + h * 64 + ds * 16 + l15] =
                    f2bf(o[qs][ds][r]);
}

// ---------------------------------------------------------------------------
// K2b: merge the 4 k-quarter partials -> AO — R0-VERBATIM.
// ---------------------------------------------------------------------------
__global__ __launch_bounds__(256) void k_merge4(
    const unsigned short* __restrict__ Op, unsigned short* __restrict__ AO)
{
    const size_t i = ((size_t)blockIdx.x * 256 + threadIdx.x) * 8;
    const size_t row = i >> 10;                 // 0..4095
    const int b = (int)(row >> 11);
    const size_t off = (row & 2047) * EMB + (i & 1023);
    float a0 = 0, a1 = 0, a2 = 0, a3 = 0, a4 = 0, a5 = 0, a6 = 0, a7 = 0;
    #pragma unroll
    for (int kq = 0; kq < 4; ++kq) {
        uint4 u = *(const uint4*)(Op + (size_t)(kq * 2 + b) * S_LEN * EMB + off);
        a0 += bflo(u.x); a1 += bfhi(u.x);
        a2 += bflo(u.y); a3 += bfhi(u.y);
        a4 += bflo(u.z); a5 += bfhi(u.z);
        a6 += bflo(u.w); a7 += bfhi(u.w);
    }
    uint4 r;
    r.x = cvtpk(a0, a1); r.y = cvtpk(a2, a3);
    r.z = cvtpk(a4, a5); r.w = cvtpk(a6, a7);
    *(uint4*)(AO + i) = r;
}

// ---------------------------------------------------------------------------
// K4: out = AO @ W_fc^T + b_fc — R0-VERBATIM (32x64 wave tile).
// ---------------------------------------------------------------------------
__global__ __launch_bounds__(256) void k_fc(
    const unsigned short* __restrict__ AO, const unsigned short* __restrict__ Wb,
    const float* __restrict__ bias, float* __restrict__ out)
{
    const int t = threadIdx.x, wave = t >> 6, lane = t & 63;
    const int l15 = lane & 15, l4 = lane >> 4;
    const int m0 = blockIdx.x * 128 + wave * 32;
    const int n0 = blockIdx.y * 64;
    v4f c[2][4];
    #pragma unroll
    for (int i = 0; i < 2; ++i)
        #pragma unroll
        for (int j = 0; j < 4; ++j) c[i][j] = (v4f){0.f, 0.f, 0.f, 0.f};
    for (int k = 0; k < EMB; k += 32) {
        v8s a0 = *(const v8s*)(AO + (size_t)(m0 + l15) * EMB + k + l4 * 8);
        v8s a1 = *(const v8s*)(AO + (size_t)(m0 + 16 + l15) * EMB + k + l4 * 8);
        #pragma unroll
        for (int ns = 0; ns < 4; ++ns) {
            v8s bw = *(const v8s*)(Wb + (size_t)(n0 + ns * 16 + l15) * EMB + k + l4 * 8);
            c[0][ns] = __builtin_amdgcn_mfma_f32_16x16x32_bf16(a0, bw, c[0][ns], 0, 0, 0);
            c[1][ns] = __builtin_amdgcn_mfma_f32_16x16x32_bf16(a1, bw, c[1][ns], 0, 0, 0);
        }
    }
    #pragma unroll
    for (int ms = 0; ms < 2; ++ms)
        #pragma unroll
        for (int ns = 0; ns < 4; ++ns) {
            const float bv = bias[n0 + ns * 16 + l15];
            #pragma unroll
            for (int r = 0; r < 4; ++r)
                out[(size_t)(m0 + ms * 16 + l4 * 4 + r) * EMB + n0 + ns * 16 + l15] = c[ms][ns][r] + bv;
        }
}

extern "C" void kernel_launch(void* const* d_in, const int* in_sizes, int n_in,
                              void* d_out, int out_size, void* d_ws, size_t ws_size,
                              hipStream_t stream)
{
    (void)in_sizes; (void)n_in; (void)out_size; (void)ws_size;
    const float* q   = (const float*)d_in[0];
    const float* k   = (const float*)d_in[1];
    const float* v   = (const float*)d_in[2];
    const float* Wq  = (const float*)d_in[3];
    const float* Wk  = (const float*)d_in[4];
    const float* Wv  = (const float*)d_in[5];
    const float* Wfc = (const float*)d_in[6];
    const float* bfc = (const float*)d_in[7];

    char* w = (char*)d_ws;
    unsigned short* Qp = (unsigned short*)(w);                      //  8 MiB (AO overlays after k_fattn)
    unsigned short* Kp = (unsigned short*)(w + (8u  << 20));        //  8 MiB
    unsigned short* Vt = (unsigned short*)(w + (16u << 20));        //  8 MiB
    unsigned short* Wb = (unsigned short*)(w + (24u << 20));        //  2 MiB
    unsigned short* Op = (unsigned short*)(w + (26u << 20));        // 32 MiB (8 planes)
    unsigned short* AO = Qp;                                        // reuse (Qp dead post-attn)

    k_proj2 <<<dim3(128, 3, 4), dim3(128),  0, stream>>>(q, k, v, Wq, Wk, Wv, Qp, Kp, Vt);
    k_cvtw  <<<dim3(1024),      dim3(256),  0, stream>>>(Wfc, Wb);
    k_fattn <<<dim3(256),       dim3(1024), 0, stream>>>(Qp, Kp, Vt, Op);
    k_merge4<<<dim3(2048),      dim3(256),  0, stream>>>(Op, AO);
    k_fc    <<<dim3(32, 16),    dim3(256),  0, stream>>>(AO, Wb, bfc, (float*)d_out);
}